// Round 10
// baseline (30.741 us; speedup 1.0000x reference)
//
#include <hip/hip_runtime.h>
#include <math.h>

// ChamferLoss via matrix cores — v_mfma_f32_32x32x16_f16 (K=16).
// Embedding:  A-side a: (ax,ay,az, 1, -|a|^2/2, 0..0)   [k=0..7, lanes 0..31]
//             B-side b: (bx,by,bz, -|b|^2/2, 1, 0..0)
// C[i][j] = a.b - (|a|^2+|b|^2)/2 = -dist^2/2 ; min dist^2 = -2 max C.
// k=8..15 operand halves are structurally zero: lanes 32..63 use a register
// zero fragment and never read LDS. LDS holds 32 row-tiles (16 KB); rows are
// swept in two build+sweep phases. 2048 blocks x 4 waves = 8 waves/SIMD.
// Kernel 1 stores per-block partials (plain store); kernel 2 reduces.

typedef _Float16 half8 __attribute__((ext_vector_type(8)));
typedef float floatx16 __attribute__((ext_vector_type(16)));

constexpr int B_ = 64;
constexpr int N_ = 2048;
constexpr int NT = N_ / 32;          // 64 row-tiles per (b,dir)
constexpr int HT = NT / 2;           // 32 tiles resident per phase
constexpr int BLOCK = 256;           // 4 waves
constexpr int WPB = 4;               // waves per block
constexpr int BFRAGS = 1;            // col-tiles per wave
constexpr int IBLK = NT / (WPB * BFRAGS);   // 16 blocks along col-tile axis
constexpr int NBLK = IBLK * B_ * 2;         // 2048 partials
constexpr int RBLOCK = 512;

__global__ __launch_bounds__(BLOCK, 8) void chamfer_mfma_kernel(
    const float* __restrict__ p, const float* __restrict__ q,
    float* __restrict__ partials)
{
    __shared__ half8 Aarr[HT * 32];      // 16 KB: 32 row-tiles, data half only
    __shared__ float wsum[WPB];

    const int dir = blockIdx.z;          // 0: A=q,B=p ; 1: A=p,B=q
    const int b   = blockIdx.y;
    const float4* rowsA = (const float4*)((dir == 0 ? q : p) + (size_t)b * N_ * 4);
    const float4* colsB = (const float4*)((dir == 0 ? p : q) + (size_t)b * N_ * 4);

    const int lane = threadIdx.x & 63;
    const int wid  = threadIdx.x >> 6;

    // B-role fragment: this wave owns col-tile (blockIdx.x * WPB + wid).
    // B frag layout: lane l holds B[k=8*(l/32)+e][col=l%32].
    half8 bf;
    {
        float4 v = colsB[(blockIdx.x * WPB + wid) * 32 + (lane & 31)];
        _Float16 x = (_Float16)v.y, y = (_Float16)v.z, z = (_Float16)v.w;
        float xf = (float)x, yf = (float)y, zf = (float)z;
        float sq = fmaf(xf, xf, fmaf(yf, yf, zf * zf));
#pragma unroll
        for (int e = 0; e < 8; ++e) bf[e] = (_Float16)0.0f;
        if (lane < 32) {
            bf[0] = x; bf[1] = y; bf[2] = z;
            bf[3] = (_Float16)(-0.5f * sq);
            bf[4] = (_Float16)1.0f;
        }
    }

    half8 zero8;
#pragma unroll
    for (int e = 0; e < 8; ++e) zero8[e] = (_Float16)0.0f;

    floatx16 zero;
#pragma unroll
    for (int i = 0; i < 16; ++i) zero[i] = 0.0f;

    float cmx = -3.4e38f;

    // Two phases: build 32 row-tiles into LDS, sweep, repeat.
    for (int ph = 0; ph < 2; ++ph) {
        __syncthreads();   // prior sweep done before overwrite (no-op at ph=0)

        // Build A fragments for rows [ph*1024, ph*1024+1024).
        for (int t = 0; t < N_ / 2; t += BLOCK) {
            const int lj = t + threadIdx.x;              // local row 0..1023
            float4 v = rowsA[ph * (N_ / 2) + lj];
            _Float16 x = (_Float16)v.y, y = (_Float16)v.z, z = (_Float16)v.w;
            float xf = (float)x, yf = (float)y, zf = (float)z;
            float sq = fmaf(xf, xf, fmaf(yf, yf, zf * zf));
            half8 lo;
            lo[0] = x; lo[1] = y; lo[2] = z; lo[3] = (_Float16)1.0f;
            lo[4] = (_Float16)(-0.5f * sq);
            lo[5] = (_Float16)0.0f; lo[6] = (_Float16)0.0f; lo[7] = (_Float16)0.0f;
            Aarr[(lj >> 5) * 32 + (lj & 31)] = lo;
        }
        __syncthreads();

        // Sweep the 32 resident row-tiles.
#pragma unroll 4
        for (int J = 0; J < HT; ++J) {
            half8 af = zero8;
            if (lane < 32) af = Aarr[J * 32 + lane];     // exec-masked ds_read
            floatx16 C = __builtin_amdgcn_mfma_f32_32x32x16_f16(af, bf, zero, 0, 0, 0);
            float m0 = fmaxf(fmaxf(C[0],  C[1]),  C[2]);
            float m1 = fmaxf(fmaxf(C[3],  C[4]),  C[5]);
            float m2 = fmaxf(fmaxf(C[6],  C[7]),  C[8]);
            float m3 = fmaxf(fmaxf(C[9],  C[10]), C[11]);
            float m4 = fmaxf(fmaxf(C[12], C[13]), C[14]);
            float m5 = fmaxf(fmaxf(m0, m1), C[15]);
            float m6 = fmaxf(fmaxf(m2, m3), m4);
            cmx = fmaxf(cmx, fmaxf(m5, m6));
        }
    }

    // Combine the two lane-halves; each column then held by 2 lanes.
    cmx = fmaxf(cmx, __shfl_xor(cmx, 32, 64));

    float local = sqrtf(fmaxf(-2.0f * cmx, 0.0f) + 1e-16f);

#pragma unroll
    for (int off = 32; off > 0; off >>= 1)
        local += __shfl_xor(local, off, 64);

    if (lane == 0) wsum[wid] = local;
    __syncthreads();
    if (threadIdx.x == 0) {
        float s = 0.0f;
#pragma unroll
        for (int w = 0; w < WPB; ++w) s += wsum[w];
        // 0.5 chamfer factor * 0.5 lane-dup; plain store, no init needed.
        partials[(blockIdx.z * B_ + blockIdx.y) * IBLK + blockIdx.x] = 0.25f * s;
    }
}

__global__ __launch_bounds__(RBLOCK) void chamfer_reduce_kernel(
    const float* __restrict__ partials, float* __restrict__ out)
{
    float v = 0.0f;
#pragma unroll
    for (int k = 0; k < NBLK / RBLOCK; ++k)
        v += partials[k * RBLOCK + threadIdx.x];

#pragma unroll
    for (int off = 32; off > 0; off >>= 1)
        v += __shfl_xor(v, off, 64);

    __shared__ float wsum[RBLOCK / 64];
    if ((threadIdx.x & 63) == 0) wsum[threadIdx.x >> 6] = v;
    __syncthreads();
    if (threadIdx.x == 0) {
        float s = 0.0f;
#pragma unroll
        for (int w = 0; w < RBLOCK / 64; ++w) s += wsum[w];
        out[0] = s;
    }
}

extern "C" void kernel_launch(void* const* d_in, const int* in_sizes, int n_in,
                              void* d_out, int out_size, void* d_ws, size_t ws_size,
                              hipStream_t stream) {
    const float* p = (const float*)d_in[0];
    const float* q = (const float*)d_in[1];
    float* out = (float*)d_out;
    float* partials = (float*)d_ws;

    dim3 grid(IBLK, B_, 2);                 // 16 x 64 x 2 = 2048 blocks
    chamfer_mfma_kernel<<<grid, BLOCK, 0, stream>>>(p, q, partials);
    chamfer_reduce_kernel<<<1, RBLOCK, 0, stream>>>(partials, out);
}

// Round 11
// 24.828 us; speedup vs baseline: 1.2382x; 1.2382x over previous
//
#include <hip/hip_runtime.h>
#include <math.h>

// ChamferLoss via matrix cores — v_mfma_f32_32x32x16_f16 (K=16).
// Embedding:  A-side a: (ax,ay,az, 1, -|a|^2/2, 0..0)   [k=0..7, lanes 0..31]
//             B-side b: (bx,by,bz, -|b|^2/2, 1, 0..0)
// C[i][j] = a.b - (|a|^2+|b|^2)/2 = -dist^2/2 ; min dist^2 = -2 max C.
// k=8..15 halves are structurally zero: lanes 32..63 use a register zero
// fragment (no LDS read). Inner loop is an explicit 2-deep software pipeline:
// tile J+1's MFMAs issue before tile J's max-tree consumes its C, so the
// matrix pipe and VALU run concurrently instead of convoy-alternating.
// Kernel 1 stores per-block partials (plain store); kernel 2 reduces.

typedef _Float16 half8 __attribute__((ext_vector_type(8)));
typedef float floatx16 __attribute__((ext_vector_type(16)));

constexpr int B_ = 64;
constexpr int N_ = 2048;
constexpr int NT = N_ / 32;        // 64 tiles per side
constexpr int BLOCK = 512;         // 8 waves
constexpr int WPB = 8;
constexpr int BFRAGS = 2;          // col-tiles per wave
constexpr int IBLK = NT / (WPB * BFRAGS);   // 4 blocks along col-tile axis
constexpr int NBLK = IBLK * B_ * 2;         // 512 partials

__device__ __forceinline__ float tree16(const floatx16& C, float acc) {
    float m0 = fmaxf(fmaxf(C[0],  C[1]),  C[2]);
    float m1 = fmaxf(fmaxf(C[3],  C[4]),  C[5]);
    float m2 = fmaxf(fmaxf(C[6],  C[7]),  C[8]);
    float m3 = fmaxf(fmaxf(C[9],  C[10]), C[11]);
    float m4 = fmaxf(fmaxf(C[12], C[13]), C[14]);
    float m5 = fmaxf(fmaxf(m0, m1), C[15]);
    float m6 = fmaxf(fmaxf(m2, m3), m4);
    return fmaxf(acc, fmaxf(m5, m6));
}

__global__ __launch_bounds__(BLOCK, 4) void chamfer_mfma_kernel(
    const float* __restrict__ p, const float* __restrict__ q,
    float* __restrict__ partials)
{
    __shared__ half8 Aarr[NT * 32];       // 32 KB: data half only
    __shared__ float wsum[WPB];

    const int dir = blockIdx.z;            // 0: A=q,B=p ; 1: A=p,B=q
    const int b   = blockIdx.y;
    const float4* rowsA = (const float4*)((dir == 0 ? q : p) + (size_t)b * N_ * 4);
    const float4* colsB = (const float4*)((dir == 0 ? p : q) + (size_t)b * N_ * 4);

    // Build all A-role fragments (data half: lanes 0..31 of each tile).
    for (int j = threadIdx.x; j < N_; j += BLOCK) {
        float4 v = rowsA[j];
        _Float16 x = (_Float16)v.y, y = (_Float16)v.z, z = (_Float16)v.w;
        float xf = (float)x, yf = (float)y, zf = (float)z;
        float sq = fmaf(xf, xf, fmaf(yf, yf, zf * zf));
        half8 lo;
        lo[0] = x; lo[1] = y; lo[2] = z; lo[3] = (_Float16)1.0f;
        lo[4] = (_Float16)(-0.5f * sq);
        lo[5] = (_Float16)0.0f; lo[6] = (_Float16)0.0f; lo[7] = (_Float16)0.0f;
        Aarr[(j >> 5) * 32 + (j & 31)] = lo;
    }

    // Two B-role fragments per wave (col-tiles 2W, 2W+1).
    const int lane = threadIdx.x & 63;
    const int wid  = threadIdx.x >> 6;
    const int W    = blockIdx.x * WPB + wid;
    half8 bf0, bf1;
    {
        float4 v = colsB[(W * BFRAGS + 0) * 32 + (lane & 31)];
        _Float16 x = (_Float16)v.y, y = (_Float16)v.z, z = (_Float16)v.w;
        float xf = (float)x, yf = (float)y, zf = (float)z;
        float sq = fmaf(xf, xf, fmaf(yf, yf, zf * zf));
#pragma unroll
        for (int e = 0; e < 8; ++e) bf0[e] = (_Float16)0.0f;
        if (lane < 32) {
            bf0[0] = x; bf0[1] = y; bf0[2] = z;
            bf0[3] = (_Float16)(-0.5f * sq);
            bf0[4] = (_Float16)1.0f;
        }
    }
    {
        float4 v = colsB[(W * BFRAGS + 1) * 32 + (lane & 31)];
        _Float16 x = (_Float16)v.y, y = (_Float16)v.z, z = (_Float16)v.w;
        float xf = (float)x, yf = (float)y, zf = (float)z;
        float sq = fmaf(xf, xf, fmaf(yf, yf, zf * zf));
#pragma unroll
        for (int e = 0; e < 8; ++e) bf1[e] = (_Float16)0.0f;
        if (lane < 32) {
            bf1[0] = x; bf1[1] = y; bf1[2] = z;
            bf1[3] = (_Float16)(-0.5f * sq);
            bf1[4] = (_Float16)1.0f;
        }
    }
    __syncthreads();

    half8 zero8;
#pragma unroll
    for (int e = 0; e < 8; ++e) zero8[e] = (_Float16)0.0f;
    floatx16 zero;
#pragma unroll
    for (int i = 0; i < 16; ++i) zero[i] = 0.0f;

    const bool lo_half = (lane < 32);

    // ---- 2-deep software pipeline over the 64 row-tiles ----
    half8 a0 = zero8;
    if (lo_half) a0 = Aarr[lane];                       // tile 0
    floatx16 P00 = __builtin_amdgcn_mfma_f32_32x32x16_f16(a0, bf0, zero, 0, 0, 0);
    floatx16 P01 = __builtin_amdgcn_mfma_f32_32x32x16_f16(a0, bf1, zero, 0, 0, 0);

    float cmx0 = -3.4e38f, cmx1 = -3.4e38f;
    for (int J = 0; J < NT; J += 2) {
        half8 t1 = zero8;
        if (lo_half) t1 = Aarr[(J + 1) * 32 + lane];
        floatx16 P10 = __builtin_amdgcn_mfma_f32_32x32x16_f16(t1, bf0, zero, 0, 0, 0);
        floatx16 P11 = __builtin_amdgcn_mfma_f32_32x32x16_f16(t1, bf1, zero, 0, 0, 0);
        cmx0 = tree16(P00, cmx0);                       // overlaps P1* MFMAs
        cmx1 = tree16(P01, cmx1);

        const int Jn = (J + 2 < NT) ? (J + 2) : 0;      // last P0* is dead
        half8 t0 = zero8;
        if (lo_half) t0 = Aarr[Jn * 32 + lane];
        P00 = __builtin_amdgcn_mfma_f32_32x32x16_f16(t0, bf0, zero, 0, 0, 0);
        P01 = __builtin_amdgcn_mfma_f32_32x32x16_f16(t0, bf1, zero, 0, 0, 0);
        cmx0 = tree16(P10, cmx0);                       // overlaps P0* MFMAs
        cmx1 = tree16(P11, cmx1);
    }

    // Combine the two lane-halves; each column then held by 2 lanes.
    cmx0 = fmaxf(cmx0, __shfl_xor(cmx0, 32, 64));
    cmx1 = fmaxf(cmx1, __shfl_xor(cmx1, 32, 64));

    float local = sqrtf(fmaxf(-2.0f * cmx0, 0.0f) + 1e-16f)
                + sqrtf(fmaxf(-2.0f * cmx1, 0.0f) + 1e-16f);

#pragma unroll
    for (int off = 32; off > 0; off >>= 1)
        local += __shfl_xor(local, off, 64);

    if (lane == 0) wsum[wid] = local;
    __syncthreads();
    if (threadIdx.x == 0) {
        float s = 0.0f;
#pragma unroll
        for (int w = 0; w < WPB; ++w) s += wsum[w];
        // 0.5 chamfer factor * 0.5 lane-dup; plain store, no init needed.
        partials[(blockIdx.z * B_ + blockIdx.y) * IBLK + blockIdx.x] = 0.25f * s;
    }
}

__global__ __launch_bounds__(NBLK) void chamfer_reduce_kernel(
    const float* __restrict__ partials, float* __restrict__ out)
{
    float v = partials[threadIdx.x];
#pragma unroll
    for (int off = 32; off > 0; off >>= 1)
        v += __shfl_xor(v, off, 64);

    __shared__ float wsum[NBLK / 64];
    if ((threadIdx.x & 63) == 0) wsum[threadIdx.x >> 6] = v;
    __syncthreads();
    if (threadIdx.x == 0) {
        float s = 0.0f;
#pragma unroll
        for (int w = 0; w < NBLK / 64; ++w) s += wsum[w];
        out[0] = s;
    }
}

extern "C" void kernel_launch(void* const* d_in, const int* in_sizes, int n_in,
                              void* d_out, int out_size, void* d_ws, size_t ws_size,
                              hipStream_t stream) {
    const float* p = (const float*)d_in[0];
    const float* q = (const float*)d_in[1];
    float* out = (float*)d_out;
    float* partials = (float*)d_ws;

    dim3 grid(IBLK, B_, 2);                 // 4 x 64 x 2 = 512 blocks
    chamfer_mfma_kernel<<<grid, BLOCK, 0, stream>>>(p, q, partials);
    chamfer_reduce_kernel<<<1, NBLK, 0, stream>>>(partials, out);
}

// Round 12
// 23.201 us; speedup vs baseline: 1.3250x; 1.0701x over previous
//
#include <hip/hip_runtime.h>
#include <math.h>

// ChamferLoss via matrix cores — v_mfma_f32_32x32x16_f16 (K=16), PACKED:
// A-fragment lanes 0..31 (k=0..7)  = rows of tile 2T   (emb in e=0..4)
// A-fragment lanes 32..63 (k=8..15)= rows of tile 2T+1 (emb in e=0..4)
// B-frag bfLO: k=0..4 = (x,y,z,-|b|^2/2,1), k>=8 zero  -> C = tile2T   x col
// B-frag bfHI: k=8..12 = same, k<8 zero               -> C = tile2T+1 x col
// So ONE full-width ds_read_b128 feeds 4 MFMAs (2 row-tiles x 2 col-tiles).
// C[i][j] = b.a - (|a|^2+|b|^2)/2 = -dist^2/2 ; min dist^2 = -2 max C.
// Kernel 1 stores per-block partials; kernel 2 reduces 512 -> scalar.

typedef _Float16 half8 __attribute__((ext_vector_type(8)));
typedef float floatx16 __attribute__((ext_vector_type(16)));

constexpr int B_ = 64;
constexpr int N_ = 2048;
constexpr int NT = N_ / 32;        // 64 row-tiles
constexpr int NPAIR = NT / 2;      // 32 packed tile-pairs
constexpr int BLOCK = 512;         // 8 waves
constexpr int WPB = 8;
constexpr int BFRAGS = 2;          // col-tiles per wave
constexpr int IBLK = NT / (WPB * BFRAGS);   // 4 blocks along col-tile axis
constexpr int NBLK = IBLK * B_ * 2;         // 512 partials

__device__ __forceinline__ float tree16(const floatx16& C, float acc) {
    float m0 = fmaxf(fmaxf(C[0],  C[1]),  C[2]);
    float m1 = fmaxf(fmaxf(C[3],  C[4]),  C[5]);
    float m2 = fmaxf(fmaxf(C[6],  C[7]),  C[8]);
    float m3 = fmaxf(fmaxf(C[9],  C[10]), C[11]);
    float m4 = fmaxf(fmaxf(C[12], C[13]), C[14]);
    float m5 = fmaxf(fmaxf(m0, m1), C[15]);
    float m6 = fmaxf(fmaxf(m2, m3), m4);
    return fmaxf(acc, fmaxf(m5, m6));
}

__global__ __launch_bounds__(BLOCK, 4) void chamfer_mfma_kernel(
    const float* __restrict__ p, const float* __restrict__ q,
    float* __restrict__ partials)
{
    __shared__ half8 Aarr[N_];            // 32 KB: Aarr[j] = emb(row j)
    __shared__ float wsum[WPB];

    const int dir = blockIdx.z;            // 0: A=q,B=p ; 1: A=p,B=q
    const int b   = blockIdx.y;
    const float4* rowsA = (const float4*)((dir == 0 ? q : p) + (size_t)b * N_ * 4);
    const float4* colsB = (const float4*)((dir == 0 ? p : q) + (size_t)b * N_ * 4);

    // Build the A-embedding table: Aarr[j] = (x,y,z,1,-|a|^2/2,0,0,0).
    for (int j = threadIdx.x; j < N_; j += BLOCK) {
        float4 v = rowsA[j];
        _Float16 x = (_Float16)v.y, y = (_Float16)v.z, z = (_Float16)v.w;
        float xf = (float)x, yf = (float)y, zf = (float)z;
        float sq = fmaf(xf, xf, fmaf(yf, yf, zf * zf));
        half8 lo;
        lo[0] = x; lo[1] = y; lo[2] = z; lo[3] = (_Float16)1.0f;
        lo[4] = (_Float16)(-0.5f * sq);
        lo[5] = (_Float16)0.0f; lo[6] = (_Float16)0.0f; lo[7] = (_Float16)0.0f;
        Aarr[j] = lo;
    }

    // Per-wave B fragments: col-tiles 2W, 2W+1; each as LO (k=0..7 lanes)
    // and HI (k=8..15 lanes) variants.
    const int lane = threadIdx.x & 63;
    const int wid  = threadIdx.x >> 6;
    const int W    = blockIdx.x * WPB + wid;
    half8 bfLO[BFRAGS], bfHI[BFRAGS];
#pragma unroll
    for (int t = 0; t < BFRAGS; ++t) {
        float4 v = colsB[(W * BFRAGS + t) * 32 + (lane & 31)];
        _Float16 x = (_Float16)v.y, y = (_Float16)v.z, z = (_Float16)v.w;
        float xf = (float)x, yf = (float)y, zf = (float)z;
        float sq = fmaf(xf, xf, fmaf(yf, yf, zf * zf));
#pragma unroll
        for (int e = 0; e < 8; ++e) { bfLO[t][e] = (_Float16)0.0f; bfHI[t][e] = (_Float16)0.0f; }
        if (lane < 32) {
            bfLO[t][0] = x; bfLO[t][1] = y; bfLO[t][2] = z;
            bfLO[t][3] = (_Float16)(-0.5f * sq);
            bfLO[t][4] = (_Float16)1.0f;
        } else {
            bfHI[t][0] = x; bfHI[t][1] = y; bfHI[t][2] = z;
            bfHI[t][3] = (_Float16)(-0.5f * sq);
            bfHI[t][4] = (_Float16)1.0f;
        }
    }
    __syncthreads();

    floatx16 zero;
#pragma unroll
    for (int i = 0; i < 16; ++i) zero[i] = 0.0f;

    // Sweep 32 tile-pairs: 1 full-width ds_read_b128 -> 4 MFMAs.
    float cmx0 = -3.4e38f, cmx1 = -3.4e38f;
#pragma unroll 2
    for (int T = 0; T < NPAIR; ++T) {
        half8 af = Aarr[T * 64 + lane];
        floatx16 C00 = __builtin_amdgcn_mfma_f32_32x32x16_f16(af, bfLO[0], zero, 0, 0, 0);
        floatx16 C01 = __builtin_amdgcn_mfma_f32_32x32x16_f16(af, bfLO[1], zero, 0, 0, 0);
        floatx16 C10 = __builtin_amdgcn_mfma_f32_32x32x16_f16(af, bfHI[0], zero, 0, 0, 0);
        floatx16 C11 = __builtin_amdgcn_mfma_f32_32x32x16_f16(af, bfHI[1], zero, 0, 0, 0);
        cmx0 = tree16(C00, cmx0);
        cmx1 = tree16(C01, cmx1);
        cmx0 = tree16(C10, cmx0);
        cmx1 = tree16(C11, cmx1);
    }

    // Combine the two lane-halves (each holds half the rows per column).
    cmx0 = fmaxf(cmx0, __shfl_xor(cmx0, 32, 64));
    cmx1 = fmaxf(cmx1, __shfl_xor(cmx1, 32, 64));

    float local = sqrtf(fmaxf(-2.0f * cmx0, 0.0f) + 1e-16f)
                + sqrtf(fmaxf(-2.0f * cmx1, 0.0f) + 1e-16f);

#pragma unroll
    for (int off = 32; off > 0; off >>= 1)
        local += __shfl_xor(local, off, 64);

    if (lane == 0) wsum[wid] = local;
    __syncthreads();
    if (threadIdx.x == 0) {
        float s = 0.0f;
#pragma unroll
        for (int w = 0; w < WPB; ++w) s += wsum[w];
        // 0.5 chamfer factor * 0.5 lane-dup; plain store, no init needed.
        partials[(blockIdx.z * B_ + blockIdx.y) * IBLK + blockIdx.x] = 0.25f * s;
    }
}

__global__ __launch_bounds__(NBLK) void chamfer_reduce_kernel(
    const float* __restrict__ partials, float* __restrict__ out)
{
    float v = partials[threadIdx.x];
#pragma unroll
    for (int off = 32; off > 0; off >>= 1)
        v += __shfl_xor(v, off, 64);

    __shared__ float wsum[NBLK / 64];
    if ((threadIdx.x & 63) == 0) wsum[threadIdx.x >> 6] = v;
    __syncthreads();
    if (threadIdx.x == 0) {
        float s = 0.0f;
#pragma unroll
        for (int w = 0; w < NBLK / 64; ++w) s += wsum[w];
        out[0] = s;
    }
}

extern "C" void kernel_launch(void* const* d_in, const int* in_sizes, int n_in,
                              void* d_out, int out_size, void* d_ws, size_t ws_size,
                              hipStream_t stream) {
    const float* p = (const float*)d_in[0];
    const float* q = (const float*)d_in[1];
    float* out = (float*)d_out;
    float* partials = (float*)d_ws;

    dim3 grid(IBLK, B_, 2);                 // 4 x 64 x 2 = 512 blocks
    chamfer_mfma_kernel<<<grid, BLOCK, 0, stream>>>(p, q, partials);
    chamfer_reduce_kernel<<<1, NBLK, 0, stream>>>(partials, out);
}